// Round 5
// baseline (436.290 us; speedup 1.0000x reference)
//
#include <hip/hip_runtime.h>

// Problem constants
#define NUM_EMB 1024
#define EMB_DIM 256
#define BATCH   32
#define HW      1024
#define Z_ELEMS (BATCH*EMB_DIM*HW)   // 8388608
#define LOSS_OFF Z_ELEMS
#define IDX_OFF (Z_ELEMS+1)

// ws layout: float[0] loss acc, uint[1] ticket, floats [16..1040) cnorm,
// [2048..34816) znorm; packed u64 argmin partials at byte 262144 (if ws fits).
#define WS_CNORM_OFF 16
#define WS_ZNORM_OFF 2048
#define WS_PACKED_BYTE_OFF 262144
#define WS_NEEDED (WS_PACKED_BYTE_OFF + 32768*8)

// ---------------------------------------------------------------------------
// K0: fused prep. Blocks 0..3: cnorm[k] (numpy pairwise tree, fp32, squares
// rounded separately, no contraction). Blocks 4..259: znorm, 2 threads per
// position (each computes one 128-d half of the tree) + init packed[n].
__global__ __launch_bounds__(256) void k_prep(const float* __restrict__ z,
                                              const float* __restrict__ cb,
                                              float* __restrict__ ws,
                                              unsigned long long* __restrict__ packed) {
    const int tid = threadIdx.x;
    if (blockIdx.x == 0 && tid == 0) { ws[0] = 0.0f; ((unsigned int*)ws)[1] = 0u; }
    if (blockIdx.x < 4) {
        int k = blockIdx.x * 256 + tid;
        const float* row = cb + (size_t)k * EMB_DIM;
        float half[2];
#pragma unroll
        for (int h = 0; h < 2; ++h) {
            const float* a = row + h * 128;
            float r[8];
#pragma unroll
            for (int j = 0; j < 8; ++j) r[j] = __fmul_rn(a[j], a[j]);
            for (int i = 8; i < 128; i += 8)
#pragma unroll
                for (int j = 0; j < 8; ++j)
                    r[j] = __fadd_rn(r[j], __fmul_rn(a[i + j], a[i + j]));
            half[h] = __fadd_rn(__fadd_rn(__fadd_rn(r[0], r[1]), __fadd_rn(r[2], r[3])),
                                __fadd_rn(__fadd_rn(r[4], r[5]), __fadd_rn(r[6], r[7])));
        }
        ws[WS_CNORM_OFF + k] = __fadd_rn(half[0], half[1]);
    } else {
        __shared__ float sh[256];
        int n = (blockIdx.x - 4) * 128 + (tid >> 1);
        int h = tid & 1;
        int b = n >> 10, p = n & 1023;
        const float* base = z + (size_t)b * EMB_DIM * HW + p;
        float r[8];
#pragma unroll
        for (int j = 0; j < 8; ++j) {
            float v = base[(size_t)(h * 128 + j) * HW];
            r[j] = __fmul_rn(v, v);
        }
        for (int i = 8; i < 128; i += 8)
#pragma unroll
            for (int j = 0; j < 8; ++j) {
                float v = base[(size_t)(h * 128 + i + j) * HW];
                r[j] = __fadd_rn(r[j], __fmul_rn(v, v));
            }
        float half = __fadd_rn(__fadd_rn(__fadd_rn(r[0], r[1]), __fadd_rn(r[2], r[3])),
                               __fadd_rn(__fadd_rn(r[4], r[5]), __fadd_rn(r[6], r[7])));
        sh[tid] = half;
        __syncthreads();
        if (h == 0) {
            ws[WS_ZNORM_OFF + n] = __fadd_rn(half, sh[tid + 1]);
            packed[n] = 0xFFFFFFFFFFFFFFFFull;
        }
    }
}

// ---------------------------------------------------------------------------
// K1: distance argmin over a 512-code half, reference fp32 rounding:
//   d = fl( fl(z2 + c2) - fl(2*dot) ), dot = serial ascending-d fma per (n,k).
// Plain scalar fmaf (fp32 VALU floor ~109us device-wide). Register-prefetch
// pipeline: global loads for chunk t+1 issue before the barrier, overlapping
// the ~2k-cycle compute of chunk t. Packed (val<<32|idx) u64 atomicMin merge.
#define MT 64
#define KC 256
#define DC 16
#define CPAD 260

__global__ __launch_bounds__(256, 4) void k_argmin(const float* __restrict__ z,
                                                   const float* __restrict__ cb,
                                                   const float* __restrict__ ws,
                                                   unsigned long long* __restrict__ packed) {
    __shared__ __attribute__((aligned(16))) float z_buf[DC * MT];    // 4 KB
    __shared__ __attribute__((aligned(16))) float c_buf[DC * CPAD];  // 16.6 KB

    const int tid = threadIdx.x;
    const int tx = tid & 15;
    const int ty = tid >> 4;          // 0..15
    const int b  = blockIdx.y;
    const int p0 = blockIdx.x * MT;
    const int kbase = blockIdx.z * 512;

    const float* zb = z + (size_t)b * EMB_DIM * HW + p0;
    const float* cn = ws + WS_CNORM_OFF;
    const float* zn = ws + WS_ZNORM_OFF + b * HW + p0;

    float z2[4];
#pragma unroll
    for (int a = 0; a < 4; ++a) z2[a] = zn[ty * 4 + a];

    float minv[4];
    int   mini[4];
#pragma unroll
    for (int a = 0; a < 4; ++a) { minv[a] = 3.402823466e+38f; mini[a] = 0; }

    // staging coords (loop-invariant)
    const int zrow = tid >> 4;            // 0..15
    const int zcol = (tid & 15) << 2;     // 0..60
    const int ckk  = tid >> 2;            // 0..63  (c row within pass)
    const int cseg = tid & 3;             // float4 slot within 16-d span

    // prefetch chunk 0 (kc=0, dc=0)
    float4 zpre = *(const float4*)(zb + (size_t)zrow * HW + zcol);
    float4 cpre[4];
#pragma unroll
    for (int p = 0; p < 4; ++p)
        cpre[p] = *(const float4*)(cb + (size_t)(kbase + p * 64 + ckk) * EMB_DIM + cseg * 4);

    float acc[4][16];
#pragma unroll
    for (int a = 0; a < 4; ++a)
#pragma unroll
        for (int q = 0; q < 16; ++q) acc[a][q] = 0.0f;

#pragma unroll 1
    for (int t = 0; t < 32; ++t) {
        const int dc = t & 15;
        const int kc = t >> 4;
        __syncthreads();   // previous compute done; LDS reusable
        *(float4*)(z_buf + zrow * MT + zcol) = zpre;
#pragma unroll
        for (int p = 0; p < 4; ++p) {
            int kk = p * 64 + ckk;
            c_buf[(cseg * 4 + 0) * CPAD + kk] = cpre[p].x;
            c_buf[(cseg * 4 + 1) * CPAD + kk] = cpre[p].y;
            c_buf[(cseg * 4 + 2) * CPAD + kk] = cpre[p].z;
            c_buf[(cseg * 4 + 3) * CPAD + kk] = cpre[p].w;
        }
        // prefetch chunk t+1 (issues before barrier; waits land next iteration)
        if (t < 31) {
            const int dc2 = (t + 1) & 15;
            const int k02 = kbase + ((t + 1) >> 4) * KC;
            zpre = *(const float4*)(zb + (size_t)(dc2 * DC + zrow) * HW + zcol);
#pragma unroll
            for (int p = 0; p < 4; ++p)
                cpre[p] = *(const float4*)(cb + (size_t)(k02 + p * 64 + ckk) * EMB_DIM + dc2 * DC + cseg * 4);
        }
        __syncthreads();   // LDS writes visible

#pragma unroll 4
        for (int d = 0; d < DC; ++d) {
            float4 za = *(const float4*)(z_buf + d * MT + ty * 4);
#pragma unroll
            for (int j = 0; j < 4; ++j) {
                float4 cv = *(const float4*)(c_buf + d * CPAD + j * 64 + tx * 4);
#pragma unroll
                for (int a = 0; a < 4; ++a) {
                    float zf = (a == 0) ? za.x : (a == 1) ? za.y : (a == 2) ? za.z : za.w;
                    acc[a][j * 4 + 0] = fmaf(zf, cv.x, acc[a][j * 4 + 0]);
                    acc[a][j * 4 + 1] = fmaf(zf, cv.y, acc[a][j * 4 + 1]);
                    acc[a][j * 4 + 2] = fmaf(zf, cv.z, acc[a][j * 4 + 2]);
                    acc[a][j * 4 + 3] = fmaf(zf, cv.w, acc[a][j * 4 + 3]);
                }
            }
        }

        if (dc == 15) {   // fold chunk's 256 codes into running argmin
            const int k0 = kbase + kc * KC;
            float c2[16];
#pragma unroll
            for (int j = 0; j < 4; ++j)
#pragma unroll
                for (int c = 0; c < 4; ++c)
                    c2[j * 4 + c] = cn[k0 + j * 64 + tx * 4 + c];
#pragma unroll
            for (int a = 0; a < 4; ++a) {
#pragma unroll
                for (int j = 0; j < 4; ++j) {
#pragma unroll
                    for (int c = 0; c < 4; ++c) {      // kg ascending per thread
                        int kg = k0 + j * 64 + tx * 4 + c;
                        float t1 = __fadd_rn(z2[a], c2[j * 4 + c]);
                        float s  = __fadd_rn(t1, __fmul_rn(-2.0f, acc[a][j * 4 + c]));
                        if (s < minv[a]) { minv[a] = s; mini[a] = kg; }  // strict <
                    }
                }
            }
#pragma unroll
            for (int a = 0; a < 4; ++a)
#pragma unroll
                for (int q = 0; q < 16; ++q) acc[a][q] = 0.0f;
        }
    }

    // cross-tx reduction (reuse c_buf), ties -> smallest index
    __syncthreads();
    float* rv = c_buf;
    int*   ri = (int*)(c_buf + 1024);
#pragma unroll
    for (int a = 0; a < 4; ++a) {
        int m = ty * 4 + a;
        rv[m * 16 + tx] = minv[a];
        ri[m * 16 + tx] = mini[a];
    }
    __syncthreads();
    if (tid < MT) {
        int m = tid;
        float bv = rv[m * 16];
        int   bi = ri[m * 16];
#pragma unroll
        for (int j = 1; j < 16; ++j) {
            float v  = rv[m * 16 + j];
            int   i2 = ri[m * 16 + j];
            if (v < bv || (v == bv && i2 < bi)) { bv = v; bi = i2; }
        }
        int n = b * HW + p0 + m;
        unsigned long long pk = ((unsigned long long)__float_as_uint(bv) << 32)
                                | (unsigned long long)(unsigned)bi;
        atomicMin(&packed[n], pk);
    }
}

// ---------------------------------------------------------------------------
// K1b (fallback only, when packed lives in out's z-region): extract indices.
__global__ __launch_bounds__(256) void k_merge(const unsigned long long* __restrict__ packed,
                                               float* __restrict__ out) {
    int n = blockIdx.x * 256 + threadIdx.x;
    out[IDX_OFF + n] = (float)(int)(unsigned)(packed[n] & 0xFFFFFFFFull);
}

// ---------------------------------------------------------------------------
// K2: gather z_q via LDS-staged codebook rows (coalesced cb reads), write
// straight-through out = fl(z + fl(z_q - z)), loss partials; fused index
// extraction + fused final scale via ticket counter.
__global__ __launch_bounds__(256) void k_gather(const float* __restrict__ z,
                                                const float* __restrict__ cb,
                                                float* __restrict__ out,
                                                float* __restrict__ ws,
                                                const unsigned long long* __restrict__ packed,
                                                int fused_idx) {
    __shared__ float s_cb[64][65];   // 16.6 KB, stride 65 -> 2-way max on reads
    __shared__ int   s_idx[64];
    __shared__ float s_red[4];
    const int tid = threadIdx.x;
    const int b  = blockIdx.x >> 4;
    const int p0 = (blockIdx.x & 15) * 64;

    if (tid < 64) {
        int n = b * HW + p0 + tid;
        int bi;
        if (fused_idx) {
            bi = (int)(unsigned)(packed[n] & 0xFFFFFFFFull);
            out[IDX_OFF + n] = (float)bi;
        } else {
            bi = (int)out[IDX_OFF + n];
        }
        s_idx[tid] = bi;
    }
    __syncthreads();

    const int p    = tid & 63;
    const int cgrp = tid >> 6;        // 0..3
    const int row  = tid >> 2;        // staging: row 0..63
    const int q4   = tid & 3;         // staging: float4 slot group
    const float* zrow = z   + (size_t)b * EMB_DIM * HW + p0 + p;
    float*       orow = out + (size_t)b * EMB_DIM * HW + p0 + p;

    float acc = 0.0f;
#pragma unroll 1
    for (int d0 = 0; d0 < EMB_DIM; d0 += 64) {
        const float* cr = cb + (size_t)s_idx[row] * EMB_DIM + d0;
#pragma unroll
        for (int pass = 0; pass < 4; ++pass) {
            int c = q4 * 4 + pass * 16;
            *(float4*)(&s_cb[row][c]) = *(const float4*)(cr + c);
        }
        __syncthreads();
#pragma unroll
        for (int j = 0; j < 16; ++j) {
            int c = cgrp * 16 + j;
            float zq = s_cb[p][c];
            float zv = zrow[(size_t)(d0 + c) * HW];
            float d  = zq - zv;
            orow[(size_t)(d0 + c) * HW] = zv + d;
            acc += d * d;
        }
        __syncthreads();   // before re-staging s_cb
    }
#pragma unroll
    for (int off = 32; off > 0; off >>= 1) acc += __shfl_down(acc, off, 64);
    if ((tid & 63) == 0) s_red[tid >> 6] = acc;
    __syncthreads();
    if (tid == 0) {
        atomicAdd(ws, s_red[0] + s_red[1] + s_red[2] + s_red[3]);
        __threadfence();
        unsigned old = atomicAdd((unsigned int*)ws + 1, 1u);
        if (old == 511u) {   // last block: all 512 loss adds visible
            float total = atomicAdd(ws, 0.0f);
            out[LOSS_OFF] = 1.25f * (total * (1.0f / 8388608.0f));
        }
    }
}

// ---------------------------------------------------------------------------
extern "C" void kernel_launch(void* const* d_in, const int* in_sizes, int n_in,
                              void* d_out, int out_size, void* d_ws, size_t ws_size,
                              hipStream_t stream) {
    const float* z  = (const float*)d_in[0];
    const float* cb = (const float*)d_in[1];
    float* out = (float*)d_out;
    float* ws  = (float*)d_ws;

    const bool big_ws = (ws_size >= (size_t)WS_NEEDED);
    unsigned long long* packed = big_ws
        ? (unsigned long long*)((char*)d_ws + WS_PACKED_BYTE_OFF)
        : (unsigned long long*)d_out;   // stage in out's z-region, merge before gather

    k_prep  <<<260, 256, 0, stream>>>(z, cb, ws, packed);
    k_argmin<<<dim3(HW / MT, BATCH, 2), 256, 0, stream>>>(z, cb, ws, packed);
    if (!big_ws)
        k_merge<<<BATCH * HW / 256, 256, 0, stream>>>(packed, out);
    k_gather<<<BATCH * (HW / 64), 256, 0, stream>>>(z, cb, out, ws, packed, big_ws ? 1 : 0);
}

// Round 6
// 307.541 us; speedup vs baseline: 1.4186x; 1.4186x over previous
//
#include <hip/hip_runtime.h>

// Problem constants
#define NUM_EMB 1024
#define EMB_DIM 256
#define BATCH   32
#define HW      1024
#define Z_ELEMS (BATCH*EMB_DIM*HW)   // 8388608
#define LOSS_OFF Z_ELEMS
#define IDX_OFF (Z_ELEMS+1)

// ws layout: float[0] loss acc, uint[1] ticket, floats [16..1040) cnorm;
// packed u64 argmin partials at byte 262144 (if ws fits).
#define WS_CNORM_OFF 16
#define WS_PACKED_BYTE_OFF 262144
#define WS_NEEDED (WS_PACKED_BYTE_OFF + 32768*8)

// ---------------------------------------------------------------------------
// K0: blocks 0..3: cnorm[k] = sum_d cb[k][d]^2 via numpy's exact pairwise tree
// (fp32, squares rounded separately, no fma contraction). Blocks 4..131: init
// packed[n] = u64max. Thread 0 zeroes loss acc + ticket.
__global__ __launch_bounds__(256) void k_prep(const float* __restrict__ cb,
                                              float* __restrict__ ws,
                                              unsigned long long* __restrict__ packed) {
    const int tid = threadIdx.x;
    if (blockIdx.x == 0 && tid == 0) { ws[0] = 0.0f; ((unsigned int*)ws)[1] = 0u; }
    if (blockIdx.x < 4) {
        int k = blockIdx.x * 256 + tid;
        const float* row = cb + (size_t)k * EMB_DIM;
        float half[2];
#pragma unroll
        for (int h = 0; h < 2; ++h) {
            const float* a = row + h * 128;
            float r[8];
#pragma unroll
            for (int j = 0; j < 8; ++j) r[j] = __fmul_rn(a[j], a[j]);
            for (int i = 8; i < 128; i += 8)
#pragma unroll
                for (int j = 0; j < 8; ++j)
                    r[j] = __fadd_rn(r[j], __fmul_rn(a[i + j], a[i + j]));
            half[h] = __fadd_rn(__fadd_rn(__fadd_rn(r[0], r[1]), __fadd_rn(r[2], r[3])),
                                __fadd_rn(__fadd_rn(r[4], r[5]), __fadd_rn(r[6], r[7])));
        }
        ws[WS_CNORM_OFF + k] = __fadd_rn(half[0], half[1]);
    } else {
        packed[(blockIdx.x - 4) * 256 + tid] = 0xFFFFFFFFFFFFFFFFull;
    }
}

// ---------------------------------------------------------------------------
// K1: distance argmin over a 512-code half, reference fp32 rounding:
//   d = fl( fl(z2 + c2) - fl(2*dot) ), dot = serial ascending-d fma per (n,k).
// 8m x 16k per-thread tile (fma : ds_read_b128 = 21.3, vs 12.8 at 4x16 --
// R4 was LDS-read-throughput-bound at 12.8). 128-position x 256-code block
// tile, DC=16 chunks. znorm computed in-kernel from the LDS z tiles during
// the first k-slab (exact numpy pairwise tree). R4 prefetch placement:
// stage-from-regs -> prefetch next -> barrier -> compute.
#define MT 128
#define KC 256
#define DC 16
#define CPAD 260

__global__ __launch_bounds__(256, 2) void k_argmin(const float* __restrict__ z,
                                                   const float* __restrict__ cb,
                                                   const float* __restrict__ ws,
                                                   unsigned long long* __restrict__ packed) {
    __shared__ __attribute__((aligned(16))) float z_buf[DC * MT];    // 8 KB
    __shared__ __attribute__((aligned(16))) float c_buf[DC * CPAD];  // 16.6 KB
    __shared__ float sh_half[2 * MT];                                // 1 KB
    __shared__ float zn_s[MT];                                       // 0.5 KB

    const int tid = threadIdx.x;
    const int tx = tid & 15;          // k: 16 codes (j*64 + tx*4 + c)
    const int ty = tid >> 4;          // m: positions ty*8 .. ty*8+7
    const int b  = blockIdx.y;
    const int p0 = blockIdx.x * MT;
    const int kbase = blockIdx.z * 512;

    const float* zb = z + (size_t)b * EMB_DIM * HW + p0;
    const float* cn = ws + WS_CNORM_OFF;

    float minv[8];
    int   mini[8];
#pragma unroll
    for (int a = 0; a < 8; ++a) { minv[a] = 3.402823466e+38f; mini[a] = 0; }

    // znorm accumulators (numpy tree chains), built from LDS during kc==0
    float r[8];
#pragma unroll
    for (int j = 0; j < 8; ++j) r[j] = 0.0f;
    const int znp = tid & 127;        // position this thread's znorm covers
    const int znh = tid >> 7;         // which 128-d half (wave-uniform)

    // staging coords (loop-invariant)
    const int zrow = tid >> 4;            // 0..15 (d row)
    const int zcol = (tid & 15) << 3;     // 0..120 (2 float4)
    const int ckk  = tid >> 2;            // 0..63 (c row within pass group)
    const int cseg = tid & 3;             // float4 slot within 16-d span

    // prefetch chunk 0 (kc=0, dc=0)
    float4 zpre0 = *(const float4*)(zb + (size_t)zrow * HW + zcol);
    float4 zpre1 = *(const float4*)(zb + (size_t)zrow * HW + zcol + 4);
    float4 cpre[4];
#pragma unroll
    for (int p = 0; p < 4; ++p)
        cpre[p] = *(const float4*)(cb + (size_t)(kbase + p * 64 + ckk) * EMB_DIM + cseg * 4);

    float acc[8][16];
#pragma unroll
    for (int a = 0; a < 8; ++a)
#pragma unroll
        for (int q = 0; q < 16; ++q) acc[a][q] = 0.0f;

#pragma unroll 1
    for (int t = 0; t < 32; ++t) {
        const int dc = t & 15;
        const int kc = t >> 4;
        __syncthreads();   // previous compute done; LDS reusable
        *(float4*)(z_buf + zrow * MT + zcol)     = zpre0;
        *(float4*)(z_buf + zrow * MT + zcol + 4) = zpre1;
#pragma unroll
        for (int p = 0; p < 4; ++p) {
            int kk = p * 64 + ckk;
            c_buf[(cseg * 4 + 0) * CPAD + kk] = cpre[p].x;
            c_buf[(cseg * 4 + 1) * CPAD + kk] = cpre[p].y;
            c_buf[(cseg * 4 + 2) * CPAD + kk] = cpre[p].z;
            c_buf[(cseg * 4 + 3) * CPAD + kk] = cpre[p].w;
        }
        // prefetch chunk t+1 (after staging, before barrier — R4 placement)
        if (t < 31) {
            const int dc2 = (t + 1) & 15;
            const int k02 = kbase + ((t + 1) >> 4) * KC;
            zpre0 = *(const float4*)(zb + (size_t)(dc2 * DC + zrow) * HW + zcol);
            zpre1 = *(const float4*)(zb + (size_t)(dc2 * DC + zrow) * HW + zcol + 4);
#pragma unroll
            for (int p = 0; p < 4; ++p)
                cpre[p] = *(const float4*)(cb + (size_t)(k02 + p * 64 + ckk) * EMB_DIM + dc2 * DC + cseg * 4);
        }
        __syncthreads();   // LDS writes visible

#pragma unroll 2
        for (int d = 0; d < DC; ++d) {
            float4 za0 = *(const float4*)(z_buf + d * MT + ty * 8);
            float4 za1 = *(const float4*)(z_buf + d * MT + ty * 8 + 4);
            float zf[8] = {za0.x, za0.y, za0.z, za0.w, za1.x, za1.y, za1.z, za1.w};
#pragma unroll
            for (int j = 0; j < 4; ++j) {
                float4 cv = *(const float4*)(c_buf + d * CPAD + j * 64 + tx * 4);
#pragma unroll
                for (int a = 0; a < 8; ++a) {
                    acc[a][j * 4 + 0] = fmaf(zf[a], cv.x, acc[a][j * 4 + 0]);
                    acc[a][j * 4 + 1] = fmaf(zf[a], cv.y, acc[a][j * 4 + 1]);
                    acc[a][j * 4 + 2] = fmaf(zf[a], cv.z, acc[a][j * 4 + 2]);
                    acc[a][j * 4 + 3] = fmaf(zf[a], cv.w, acc[a][j * 4 + 3]);
                }
            }
        }

        // znorm chains from this z tile (kc==0 only; wave-uniform h match).
        // chunk dc covers dims dc*16..dc*16+15; within-half index i = d - h*128,
        // chain j = i & 7 = e & 7, e ascending keeps numpy's serial order.
        if (kc == 0 && (dc >> 3) == znh) {
#pragma unroll
            for (int e = 0; e < 16; ++e) {
                float v = z_buf[e * MT + znp];
                r[e & 7] = __fadd_rn(r[e & 7], __fmul_rn(v, v));
            }
        }

        if (dc == 15) {   // end of a 256-code slab
            if (kc == 0) {
                // finish znorm: combine chains exactly like numpy's tree
                float s01 = __fadd_rn(__fadd_rn(r[0], r[1]), __fadd_rn(r[2], r[3]));
                float s23 = __fadd_rn(__fadd_rn(r[4], r[5]), __fadd_rn(r[6], r[7]));
                sh_half[znh * MT + znp] = __fadd_rn(s01, s23);
                __syncthreads();
                if (tid < MT) zn_s[tid] = __fadd_rn(sh_half[tid], sh_half[MT + tid]);
                __syncthreads();
            }
            // fold slab's 256 codes into running argmin (reference rounding)
            const int k0 = kbase + kc * KC;
            float c2[16];
#pragma unroll
            for (int j = 0; j < 4; ++j)
#pragma unroll
                for (int c = 0; c < 4; ++c)
                    c2[j * 4 + c] = cn[k0 + j * 64 + tx * 4 + c];
            float z2[8];
#pragma unroll
            for (int a = 0; a < 8; ++a) z2[a] = zn_s[ty * 8 + a];
#pragma unroll
            for (int a = 0; a < 8; ++a) {
#pragma unroll
                for (int j = 0; j < 4; ++j) {
#pragma unroll
                    for (int c = 0; c < 4; ++c) {      // kg ascending per thread
                        int kg = k0 + j * 64 + tx * 4 + c;
                        float t1 = __fadd_rn(z2[a], c2[j * 4 + c]);
                        float s  = __fadd_rn(t1, __fmul_rn(-2.0f, acc[a][j * 4 + c]));
                        if (s < minv[a]) { minv[a] = s; mini[a] = kg; }  // strict <
                    }
                }
            }
#pragma unroll
            for (int a = 0; a < 8; ++a)
#pragma unroll
                for (int q = 0; q < 16; ++q) acc[a][q] = 0.0f;
        }
    }

    // cross-tx reduction (reuse c_buf: 2048 floats + 2048 ints <= 4160)
    __syncthreads();
    float* rv = c_buf;
    int*   ri = (int*)(c_buf + 2048);
#pragma unroll
    for (int a = 0; a < 8; ++a) {
        int m = ty * 8 + a;
        rv[m * 16 + tx] = minv[a];
        ri[m * 16 + tx] = mini[a];
    }
    __syncthreads();
    if (tid < MT) {
        int m = tid;
        float bv = rv[m * 16];
        int   bi = ri[m * 16];
#pragma unroll
        for (int j = 1; j < 16; ++j) {
            float v  = rv[m * 16 + j];
            int   i2 = ri[m * 16 + j];
            if (v < bv || (v == bv && i2 < bi)) { bv = v; bi = i2; }
        }
        int n = b * HW + p0 + m;
        unsigned long long pk = ((unsigned long long)__float_as_uint(bv) << 32)
                                | (unsigned long long)(unsigned)bi;
        atomicMin(&packed[n], pk);
    }
}

// ---------------------------------------------------------------------------
// K1b (fallback only, when packed lives in out's z-region): extract indices.
__global__ __launch_bounds__(256) void k_merge(const unsigned long long* __restrict__ packed,
                                               float* __restrict__ out) {
    int n = blockIdx.x * 256 + threadIdx.x;
    out[IDX_OFF + n] = (float)(int)(unsigned)(packed[n] & 0xFFFFFFFFull);
}

// ---------------------------------------------------------------------------
// K2: gather z_q via LDS-staged codebook rows (coalesced cb reads), write
// straight-through out = fl(z + fl(z_q - z)), loss partials; fused index
// extraction + fused final scale via ticket counter.
__global__ __launch_bounds__(256) void k_gather(const float* __restrict__ z,
                                                const float* __restrict__ cb,
                                                float* __restrict__ out,
                                                float* __restrict__ ws,
                                                const unsigned long long* __restrict__ packed,
                                                int fused_idx) {
    __shared__ float s_cb[64][65];   // 16.6 KB, stride 65 -> 2-way max on reads
    __shared__ int   s_idx[64];
    __shared__ float s_red[4];
    const int tid = threadIdx.x;
    const int b  = blockIdx.x >> 4;
    const int p0 = (blockIdx.x & 15) * 64;

    if (tid < 64) {
        int n = b * HW + p0 + tid;
        int bi;
        if (fused_idx) {
            bi = (int)(unsigned)(packed[n] & 0xFFFFFFFFull);
            out[IDX_OFF + n] = (float)bi;
        } else {
            bi = (int)out[IDX_OFF + n];
        }
        s_idx[tid] = bi;
    }
    __syncthreads();

    const int p    = tid & 63;
    const int cgrp = tid >> 6;        // 0..3
    const int row  = tid >> 2;        // staging: row 0..63
    const int q4   = tid & 3;         // staging: float4 slot group
    const float* zrow = z   + (size_t)b * EMB_DIM * HW + p0 + p;
    float*       orow = out + (size_t)b * EMB_DIM * HW + p0 + p;

    float acc = 0.0f;
#pragma unroll 1
    for (int d0 = 0; d0 < EMB_DIM; d0 += 64) {
        const float* cr = cb + (size_t)s_idx[row] * EMB_DIM + d0;
#pragma unroll
        for (int pass = 0; pass < 4; ++pass) {
            int c = q4 * 4 + pass * 16;
            *(float4*)(&s_cb[row][c]) = *(const float4*)(cr + c);
        }
        __syncthreads();
#pragma unroll
        for (int j = 0; j < 16; ++j) {
            int c = cgrp * 16 + j;
            float zq = s_cb[p][c];
            float zv = zrow[(size_t)(d0 + c) * HW];
            float d  = zq - zv;
            orow[(size_t)(d0 + c) * HW] = zv + d;
            acc += d * d;
        }
        __syncthreads();   // before re-staging s_cb
    }
#pragma unroll
    for (int off = 32; off > 0; off >>= 1) acc += __shfl_down(acc, off, 64);
    if ((tid & 63) == 0) s_red[tid >> 6] = acc;
    __syncthreads();
    if (tid == 0) {
        atomicAdd(ws, s_red[0] + s_red[1] + s_red[2] + s_red[3]);
        __threadfence();
        unsigned old = atomicAdd((unsigned int*)ws + 1, 1u);
        if (old == 511u) {   // last block: all 512 loss adds visible
            float total = atomicAdd(ws, 0.0f);
            out[LOSS_OFF] = 1.25f * (total * (1.0f / 8388608.0f));
        }
    }
}

// ---------------------------------------------------------------------------
extern "C" void kernel_launch(void* const* d_in, const int* in_sizes, int n_in,
                              void* d_out, int out_size, void* d_ws, size_t ws_size,
                              hipStream_t stream) {
    const float* z  = (const float*)d_in[0];
    const float* cb = (const float*)d_in[1];
    float* out = (float*)d_out;
    float* ws  = (float*)d_ws;

    const bool big_ws = (ws_size >= (size_t)WS_NEEDED);
    unsigned long long* packed = big_ws
        ? (unsigned long long*)((char*)d_ws + WS_PACKED_BYTE_OFF)
        : (unsigned long long*)d_out;   // stage in out's z-region, merge before gather

    k_prep  <<<132, 256, 0, stream>>>(cb, ws, packed);
    k_argmin<<<dim3(HW / MT, BATCH, 2), 256, 0, stream>>>(z, cb, ws, packed);
    if (!big_ws)
        k_merge<<<BATCH * HW / 256, 256, 0, stream>>>(packed, out);
    k_gather<<<BATCH * (HW / 64), 256, 0, stream>>>(z, cb, out, ws, packed, big_ws ? 1 : 0);
}